// Round 9
// baseline (3746.857 us; speedup 1.0000x reference)
//
#include <hip/hip_runtime.h>
#include <math.h>

// Sizes fixed by the problem
#define N_PTS   8192
#define BATCH   2
#define DIM     128
#define NOUT    2048
#define FPOFF   1048576   // 2048*2*256 floats of output 0
#define SLICE_MAX 512

__device__ __forceinline__ float gelu_f(float v) {
  return 0.5f * v * (1.0f + erff(v * 0.70710678118654752440f));
}

// ---------------------------------------------------------------------------
// stable sorted top-8 insert, reference tie semantics (earlier index wins)
// ---------------------------------------------------------------------------
__device__ __forceinline__ void knn_insert(float (&dist)[8], int (&idq)[8],
                                           float d2, int ci) {
  if (d2 < dist[7]) {
    float dd = d2;
#pragma unroll
    for (int j = 0; j < 8; ++j) {
      bool cc = dd < dist[j];
      float td = dist[j]; int ti = idq[j];
      dist[j] = cc ? dd : td; idq[j] = cc ? ci : ti;
      dd = cc ? td : dd; ci = cc ? ti : ci;
    }
  }
}

// ---------------------------------------------------------------------------
// FPS slice, 512 threads, 16 slots/thread (R4-proven logic; 1.09 us/iter).
// Hosts run this for blockIdx.x < 2 so fps waves start at t=0 of each launch.
// Per-thread (value, earliest-slot) fold; u64 key (d_bits<<32)|~gidx;
// 6-stage wave butterfly; 8-key block scan via parity LDS + ONE barrier;
// winner coords fetched from global P (L2-hot broadcast; P is input-only so
// no scalar-cache coherence hazard). State (mind, lp) persists in ws.
// Reference-exact: no-FMA fp32, (dx^2+dy^2)+dz^2, fminf, first-index
// tie-break via ~gidx under u64 max.
// ---------------------------------------------------------------------------
__device__ __forceinline__ void fps_slice(
    const float* __restrict__ P, float* __restrict__ MWS, float* __restrict__ LPWS,
    float* __restrict__ FPWS, float* __restrict__ OUTFP,
    int b, int t0, int t1)
{
  __builtin_amdgcn_s_setprio(3);
  __shared__ unsigned long long wkeys[2][8];
  __shared__ float hist[SLICE_MAX * 3];
  const int tid = threadIdx.x;          // 0..511
  const int wv = tid >> 6;              // 0..7
  const float* __restrict__ Pb = P + (long)b * N_PTS * 3;
  float px[16], py[16], pz[16], mind[16];
#pragma unroll
  for (int s = 0; s < 16; ++s) {
    int i = s * 512 + tid;
    px[s] = Pb[i * 3 + 0];
    py[s] = Pb[i * 3 + 1];
    pz[s] = Pb[i * 3 + 2];
  }
  float lx, ly, lz;
  if (t0 == 0) {
#pragma unroll
    for (int s = 0; s < 16; ++s) mind[s] = INFINITY;
    lx = Pb[0]; ly = Pb[1]; lz = Pb[2];
    if (tid == 0) { hist[0] = lx; hist[1] = ly; hist[2] = lz; }
  } else {
#pragma unroll
    for (int s = 0; s < 16; ++s) mind[s] = MWS[b * N_PTS + s * 512 + tid];
    lx = LPWS[b * 4 + 0]; ly = LPWS[b * 4 + 1]; lz = LPWS[b * 4 + 2];
  }
  const int tstart = (t0 == 0) ? 1 : t0;
  for (int t = tstart; t < t1; ++t) {
    const int par = t & 1;
    float bv = -INFINITY; int bs = 0;
#pragma unroll
    for (int s = 0; s < 16; ++s) {
      float dx = __fsub_rn(px[s], lx);
      float dy = __fsub_rn(py[s], ly);
      float dz = __fsub_rn(pz[s], lz);
      float d = __fadd_rn(__fadd_rn(__fmul_rn(dx, dx), __fmul_rn(dy, dy)), __fmul_rn(dz, dz));
      float mm = fminf(mind[s], d);
      mind[s] = mm;
      bool c = mm > bv;                 // strict > : earliest slot (smallest gidx) wins
      bv = c ? mm : bv; bs = c ? s : bs;
    }
    unsigned long long key =
        ((unsigned long long)__float_as_uint(bv) << 32) |
        (unsigned int)~(unsigned int)(bs * 512 + tid);
#pragma unroll
    for (int off = 1; off <= 32; off <<= 1) {
      unsigned long long o = __shfl_xor(key, off);
      key = (o > key) ? o : key;
    }
    if ((tid & 63) == 0) wkeys[par][wv] = key;   // all lanes converged; lane0 writes
    __syncthreads();
    unsigned long long wk = wkeys[par][0];
#pragma unroll
    for (int u = 1; u < 8; ++u) {
      unsigned long long o = wkeys[par][u];
      wk = (o > wk) ? o : wk;
    }
    const int idx = (int)(~(unsigned int)wk);    // lo32 = ~gidx
    lx = Pb[idx * 3 + 0];
    ly = Pb[idx * 3 + 1];
    lz = Pb[idx * 3 + 2];
    if (tid == 0) {
      int h = (t - t0) * 3;
      hist[h + 0] = lx; hist[h + 1] = ly; hist[h + 2] = lz;
    }
    // next iteration writes the other parity buffer -> one barrier suffices
  }
  // persist state
#pragma unroll
  for (int s = 0; s < 16; ++s) MWS[b * N_PTS + s * 512 + tid] = mind[s];
  if (tid == 0) { LPWS[b * 4 + 0] = lx; LPWS[b * 4 + 1] = ly; LPWS[b * 4 + 2] = lz; }
  __syncthreads();
  const int cnt = (t1 - t0) * 3;
  const long base = ((long)b * NOUT + t0) * 3;
  for (int i = tid; i < cnt; i += 512) {
    float v2 = hist[i];
    FPWS[base + i] = v2;
    OUTFP[FPOFF + base + i] = v2;
  }
  __builtin_amdgcn_s_setprio(0);
}

// standalone finisher
__global__ __launch_bounds__(512) void fps_fin(
    const float* __restrict__ P, float* __restrict__ MWS, float* __restrict__ LPWS,
    float* __restrict__ FPWS, float* __restrict__ OUTFP, int t0, int t1)
{
  fps_slice(P, MWS, LPWS, FPWS, OUTFP, blockIdx.x, t0, t1);
}

// ---------------------------------------------------------------------------
// Fused-pair fp32 GEMM host (512 threads = 2 teams x 256); blocks 0,1 = fps.
// Per team: 128x128 tile, BK=16, 8x(4+4) micro-tile (R4-proven).
// wid = bid-2: bx = wid%nbx, byy = (wid/nbx)*2+team.
// a_mode: 0 direct; 1 arow=(r&8191)*2+(r>>13)
// o_mode: 0 direct; 1 orow=(r&8191)*2+(r>>13); 2 orow=(r&1)*8192+(r>>1)
// ---------------------------------------------------------------------------
__global__ __launch_bounds__(512) void gemm2_k(
    const float* __restrict__ A, const float* __restrict__ W,
    const float* __restrict__ bias, float* __restrict__ OUT,
    const float* __restrict__ resid,
    int nbx, int N, int K, int a_mode, int o_mode, int act,
    const float* __restrict__ P, float* __restrict__ MWS, float* __restrict__ LPWS,
    float* __restrict__ FPWS, float* __restrict__ OUTFP, int t0, int t1)
{
  if ((int)blockIdx.x < 2) {
    fps_slice(P, MWS, LPWS, FPWS, OUTFP, (int)blockIdx.x, t0, t1);
    return;
  }
  const int wid = (int)blockIdx.x - 2;
  __shared__ float As[2][16][132];
  __shared__ float Ws2[2][16][132];
  const int team = threadIdx.x >> 8;
  const int tid = threadIdx.x & 255;
  const int tx = tid & 15, ty = tid >> 4;
  const int bx = wid % nbx;
  const int byy = (wid / nbx) * 2 + team;
  float acc[8][8];
#pragma unroll
  for (int i = 0; i < 8; ++i)
#pragma unroll
    for (int j = 0; j < 8; ++j) acc[i][j] = 0.f;

  for (int k0 = 0; k0 < K; k0 += 16) {
#pragma unroll
    for (int rep = 0; rep < 2; ++rep) {
      int qq = tid + rep * 256;          // 0..511
      int m = qq >> 2, kq = qq & 3;      // A: 128 rows x 16k as float4
      int r = byy * 128 + m;
      int arow = (a_mode == 1) ? ((r & 8191) * 2 + (r >> 13)) : r;
      const float4 av = *(const float4*)(A + (long)arow * K + k0 + kq * 4);
      As[team][kq * 4 + 0][m] = av.x; As[team][kq * 4 + 1][m] = av.y;
      As[team][kq * 4 + 2][m] = av.z; As[team][kq * 4 + 3][m] = av.w;
      int kw = qq >> 5, nq = qq & 31;    // W: 16k x 128 cols
      const float4 wv = *(const float4*)(W + (long)(k0 + kw) * N + bx * 128 + nq * 4);
      *(float4*)&Ws2[team][kw][nq * 4] = wv;
    }
    __syncthreads();
#pragma unroll
    for (int kk = 0; kk < 16; ++kk) {
      float4 a0 = *(const float4*)&As[team][kk][ty * 8];
      float4 a1 = *(const float4*)&As[team][kk][ty * 8 + 4];
      float4 w0 = *(const float4*)&Ws2[team][kk][tx * 4];
      float4 w1 = *(const float4*)&Ws2[team][kk][64 + tx * 4];
      float am[8] = {a0.x, a0.y, a0.z, a0.w, a1.x, a1.y, a1.z, a1.w};
      float wn[8] = {w0.x, w0.y, w0.z, w0.w, w1.x, w1.y, w1.z, w1.w};
#pragma unroll
      for (int i = 0; i < 8; ++i)
#pragma unroll
        for (int j = 0; j < 8; ++j) acc[i][j] += am[i] * wn[j];
    }
    __syncthreads();
  }
  const int c0 = bx * 128 + tx * 4;
  const int c1 = c0 + 64;
  float4 ba = *(const float4*)(bias + c0);
  float4 bb = *(const float4*)(bias + c1);
#pragma unroll
  for (int i = 0; i < 8; ++i) {
    int r = byy * 128 + ty * 8 + i;
    int orow = (o_mode == 1) ? ((r & 8191) * 2 + (r >> 13))
             : (o_mode == 2) ? ((r & 1) * 8192 + (r >> 1)) : r;
    float o[8] = {acc[i][0] + ba.x, acc[i][1] + ba.y, acc[i][2] + ba.z, acc[i][3] + ba.w,
                  acc[i][4] + bb.x, acc[i][5] + bb.y, acc[i][6] + bb.z, acc[i][7] + bb.w};
    if (act == 1) {
#pragma unroll
      for (int j = 0; j < 8; ++j) o[j] = gelu_f(o[j]);
    }
    if (resid) {
      float4 r0 = *(const float4*)(resid + (long)orow * N + c0);
      float4 r1 = *(const float4*)(resid + (long)orow * N + c1);
      o[0] += r0.x; o[1] += r0.y; o[2] += r0.z; o[3] += r0.w;
      o[4] += r1.x; o[5] += r1.y; o[6] += r1.z; o[7] += r1.w;
    }
    *(float4*)(OUT + (long)orow * N + c0) = make_float4(o[0], o[1], o[2], o[3]);
    *(float4*)(OUT + (long)orow * N + c1) = make_float4(o[4], o[5], o[6], o[7]);
  }
}

// ---------------------------------------------------------------------------
// KNN self, STANDALONE 64-thr blocks x 256 blocks (grid 128 x 2) — one wave
// per CU, full chip width. Batch-4 candidate loop (R8-proven), LDS staging.
// d2 = (|q|^2+|p|^2) - 2*dot, stable sorted top-8, no-FMA reference math.
// ---------------------------------------------------------------------------
__global__ __launch_bounds__(64) void knn1_k(
    const float* __restrict__ Q, const float* __restrict__ P,
    int* __restrict__ OUTI)
{
  __shared__ float4 shp[512];
  const int b = blockIdx.y;
  const int m = blockIdx.x * 64 + threadIdx.x;
  const float qx = Q[(b * N_PTS + m) * 3 + 0];
  const float qy = Q[(b * N_PTS + m) * 3 + 1];
  const float qz = Q[(b * N_PTS + m) * 3 + 2];
  const float sqq = __fadd_rn(__fadd_rn(__fmul_rn(qx, qx), __fmul_rn(qy, qy)), __fmul_rn(qz, qz));
  float dist[8]; int idq[8];
#pragma unroll
  for (int j = 0; j < 8; ++j) { dist[j] = INFINITY; idq[j] = 0; }
  for (int tt = 0; tt < N_PTS; tt += 512) {
    __syncthreads();
    for (int l = threadIdx.x; l < 512; l += 64) {
      float x = P[(b * N_PTS + tt + l) * 3 + 0];
      float y = P[(b * N_PTS + tt + l) * 3 + 1];
      float z = P[(b * N_PTS + tt + l) * 3 + 2];
      float s = __fadd_rn(__fadd_rn(__fmul_rn(x, x), __fmul_rn(y, y)), __fmul_rn(z, z));
      shp[l] = make_float4(x, y, z, s);
    }
    __syncthreads();
    for (int c = 0; c < 512; c += 4) {
      float4 p0 = shp[c + 0];
      float4 p1 = shp[c + 1];
      float4 p2 = shp[c + 2];
      float4 p3 = shp[c + 3];
      float d0 = __fsub_rn(__fadd_rn(sqq, p0.w), __fmul_rn(2.0f,
                 __fadd_rn(__fadd_rn(__fmul_rn(qx, p0.x), __fmul_rn(qy, p0.y)), __fmul_rn(qz, p0.z))));
      float d1 = __fsub_rn(__fadd_rn(sqq, p1.w), __fmul_rn(2.0f,
                 __fadd_rn(__fadd_rn(__fmul_rn(qx, p1.x), __fmul_rn(qy, p1.y)), __fmul_rn(qz, p1.z))));
      float d2 = __fsub_rn(__fadd_rn(sqq, p2.w), __fmul_rn(2.0f,
                 __fadd_rn(__fadd_rn(__fmul_rn(qx, p2.x), __fmul_rn(qy, p2.y)), __fmul_rn(qz, p2.z))));
      float d3 = __fsub_rn(__fadd_rn(sqq, p3.w), __fmul_rn(2.0f,
                 __fadd_rn(__fadd_rn(__fmul_rn(qx, p3.x), __fmul_rn(qy, p3.y)), __fmul_rn(qz, p3.z))));
      float mn = fminf(fminf(d0, d1), fminf(d2, d3));
      if (mn < dist[7]) {                // rare path; inserts in index order
        knn_insert(dist, idq, d0, tt + c + 0);
        knn_insert(dist, idq, d1, tt + c + 1);
        knn_insert(dist, idq, d2, tt + c + 2);
        knn_insert(dist, idq, d3, tt + c + 3);
      }
    }
  }
#pragma unroll
  for (int j = 0; j < 8; ++j) OUTI[(long)(b * N_PTS + m) * 8 + j] = idq[j];
}

// ---------------------------------------------------------------------------
// KNN of fp_pos vs all points, standalone 64-thr blocks, batch-4 inner loop.
// ---------------------------------------------------------------------------
__global__ __launch_bounds__(64) void knn2_k(
    const float* __restrict__ Q, const float* __restrict__ P,
    int* __restrict__ OUTI)
{
  __shared__ float4 shp[512];
  const int b = blockIdx.y;
  const int m = blockIdx.x * 64 + threadIdx.x;
  const float qx = Q[(b * NOUT + m) * 3 + 0];
  const float qy = Q[(b * NOUT + m) * 3 + 1];
  const float qz = Q[(b * NOUT + m) * 3 + 2];
  const float sqq = __fadd_rn(__fadd_rn(__fmul_rn(qx, qx), __fmul_rn(qy, qy)), __fmul_rn(qz, qz));
  float dist[8]; int idq[8];
#pragma unroll
  for (int j = 0; j < 8; ++j) { dist[j] = INFINITY; idq[j] = 0; }
  for (int tt = 0; tt < N_PTS; tt += 512) {
    __syncthreads();
    for (int l = threadIdx.x; l < 512; l += 64) {
      float x = P[(b * N_PTS + tt + l) * 3 + 0];
      float y = P[(b * N_PTS + tt + l) * 3 + 1];
      float z = P[(b * N_PTS + tt + l) * 3 + 2];
      float s = __fadd_rn(__fadd_rn(__fmul_rn(x, x), __fmul_rn(y, y)), __fmul_rn(z, z));
      shp[l] = make_float4(x, y, z, s);
    }
    __syncthreads();
    for (int c = 0; c < 512; c += 4) {
      float4 p0 = shp[c + 0];
      float4 p1 = shp[c + 1];
      float4 p2 = shp[c + 2];
      float4 p3 = shp[c + 3];
      float d0 = __fsub_rn(__fadd_rn(sqq, p0.w), __fmul_rn(2.0f,
                 __fadd_rn(__fadd_rn(__fmul_rn(qx, p0.x), __fmul_rn(qy, p0.y)), __fmul_rn(qz, p0.z))));
      float d1 = __fsub_rn(__fadd_rn(sqq, p1.w), __fmul_rn(2.0f,
                 __fadd_rn(__fadd_rn(__fmul_rn(qx, p1.x), __fmul_rn(qy, p1.y)), __fmul_rn(qz, p1.z))));
      float d2 = __fsub_rn(__fadd_rn(sqq, p2.w), __fmul_rn(2.0f,
                 __fadd_rn(__fadd_rn(__fmul_rn(qx, p2.x), __fmul_rn(qy, p2.y)), __fmul_rn(qz, p2.z))));
      float d3 = __fsub_rn(__fadd_rn(sqq, p3.w), __fmul_rn(2.0f,
                 __fadd_rn(__fadd_rn(__fmul_rn(qx, p3.x), __fmul_rn(qy, p3.y)), __fmul_rn(qz, p3.z))));
      float mn = fminf(fminf(d0, d1), fminf(d2, d3));
      if (mn < dist[7]) {
        knn_insert(dist, idq, d0, tt + c + 0);
        knn_insert(dist, idq, d1, tt + c + 1);
        knn_insert(dist, idq, d2, tt + c + 2);
        knn_insert(dist, idq, d3, tt + c + 3);
      }
    }
  }
#pragma unroll
  for (int j = 0; j < 8; ++j) OUTI[(long)(b * NOUT + m) * 8 + j] = idq[j];
}

// ---------------------------------------------------------------------------
// Fused neighbor attention, 512-thr host (8 waves = 8 points); blocks 0,1=fps.
// ---------------------------------------------------------------------------
__global__ __launch_bounds__(512) void attn_k(
    const float* __restrict__ Qb, const float* __restrict__ Kb, const float* __restrict__ Vb,
    const float* __restrict__ Pp, const int* __restrict__ IDX,
    const float* __restrict__ Wpe1, const float* __restrict__ bpe1,
    const float* __restrict__ Wpe2, const float* __restrict__ bpe2,
    const float* __restrict__ Wg, const float* __restrict__ bg,
    float* __restrict__ RES,
    const float* __restrict__ P, float* __restrict__ MWS, float* __restrict__ LPWS,
    float* __restrict__ FPWS, float* __restrict__ OUTFP, int t0, int t1)
{
  if ((int)blockIdx.x < 2) {
    fps_slice(P, MWS, LPWS, FPWS, OUTFP, (int)blockIdx.x, t0, t1);
    return;
  }
  __shared__ float sbuf[8][1024];
  const int tid = threadIdx.x;
  const int w = tid >> 6, lane = tid & 63;
  const int g = ((int)blockIdx.x - 2) * 8 + w;   // 0..16383 : b*8192+n
  const int b = g >> 13, n = g & 8191;
  const int j0 = lane * 2;
  float* sb = sbuf[w];
  const float2 qv = *(const float2*)(Qb + (long)g * 128 + j0);
  int nb[8];
#pragma unroll
  for (int kk = 0; kk < 8; ++kk) nb[kk] = IDX[g * 8 + kk];
  const float p0 = Pp[(b * N_PTS + n) * 3 + 0];
  const float p1 = Pp[(b * N_PTS + n) * 3 + 1];
  const float p2 = Pp[(b * N_PTS + n) * 3 + 2];
  // phase A: h1 = gelu(rel @ Wpe1 + bpe1) -> LDS
  const float2 w1a = *(const float2*)(Wpe1 + j0);
  const float2 w1b = *(const float2*)(Wpe1 + 128 + j0);
  const float2 w1c = *(const float2*)(Wpe1 + 256 + j0);
  const float2 b1 = *(const float2*)(bpe1 + j0);
#pragma unroll
  for (int kk = 0; kk < 8; ++kk) {
    const float* pn = Pp + (long)(b * N_PTS + nb[kk]) * 3;
    float r0 = p0 - pn[0], r1 = p1 - pn[1], r2 = p2 - pn[2];
    float h0 = r0 * w1a.x + r1 * w1b.x + r2 * w1c.x + b1.x;
    float h1 = r0 * w1a.y + r1 * w1b.y + r2 * w1c.y + b1.y;
    sb[kk * 128 + j0]     = gelu_f(h0);
    sb[kk * 128 + j0 + 1] = gelu_f(h1);
  }
  __syncthreads();
  // phase B: pe = h1 @ Wpe2
  float2 pe[8];
#pragma unroll
  for (int kk = 0; kk < 8; ++kk) pe[kk] = make_float2(0.f, 0.f);
  for (int i = 0; i < 128; i += 2) {
    float2 wa = *(const float2*)(Wpe2 + (long)i * 128 + j0);
    float2 wb = *(const float2*)(Wpe2 + (long)(i + 1) * 128 + j0);
#pragma unroll
    for (int kk = 0; kk < 8; ++kk) {
      float2 hh = *(const float2*)&sb[kk * 128 + i];
      pe[kk].x += hh.x * wa.x + hh.y * wb.x;
      pe[kk].y += hh.x * wa.y + hh.y * wb.y;
    }
  }
  const float2 b2v = *(const float2*)(bpe2 + j0);
  __syncthreads();
  // t = q - k_nb + pe  -> LDS (reuse buffer)
#pragma unroll
  for (int kk = 0; kk < 8; ++kk) {
    pe[kk].x += b2v.x; pe[kk].y += b2v.y;
    const float2 kv = *(const float2*)(Kb + (long)(b * N_PTS + nb[kk]) * 128 + j0);
    sb[kk * 128 + j0]     = qv.x - kv.x + pe[kk].x;
    sb[kk * 128 + j0 + 1] = qv.y - kv.y + pe[kk].y;
  }
  __syncthreads();
  // phase C: a = t @ Wg
  float2 av[8];
#pragma unroll
  for (int kk = 0; kk < 8; ++kk) av[kk] = make_float2(0.f, 0.f);
  for (int i = 0; i < 128; i += 2) {
    float2 wa = *(const float2*)(Wg + (long)i * 128 + j0);
    float2 wb = *(const float2*)(Wg + (long)(i + 1) * 128 + j0);
#pragma unroll
    for (int kk = 0; kk < 8; ++kk) {
      float2 tt = *(const float2*)&sb[kk * 128 + i];
      av[kk].x += tt.x * wa.x + tt.y * wb.x;
      av[kk].y += tt.x * wa.y + tt.y * wb.y;
    }
  }
  const float2 bgv = *(const float2*)(bg + j0);
  float2 resv = make_float2(0.f, 0.f);
  const float sd = 11.313708498984761f;   // sqrt(128)
#pragma unroll
  for (int kk = 0; kk < 8; ++kk) {
    float l0 = (av[kk].x + bgv.x) / sd;
    float l1 = (av[kk].y + bgv.y) / sd;
    float mx = fmaxf(l0, l1);
#pragma unroll
    for (int off = 32; off >= 1; off >>= 1) mx = fmaxf(mx, __shfl_xor(mx, off));
    float e0 = expf(l0 - mx), e1 = expf(l1 - mx);
    float sm = e0 + e1;
#pragma unroll
    for (int off = 32; off >= 1; off >>= 1) sm += __shfl_xor(sm, off);
    const float2 vv = *(const float2*)(Vb + (long)(b * N_PTS + nb[kk]) * 128 + j0);
    resv.x += (e0 / sm) * (vv.x + pe[kk].x);
    resv.y += (e1 / sm) * (vv.y + pe[kk].y);
  }
  *(float2*)(RES + (long)g * 128 + j0) = resv;
}

// ---------------------------------------------------------------------------
// RMSNorm in-place, 512-thr host (8 rows/block); blocks 0,1 = fps.
// ---------------------------------------------------------------------------
__global__ __launch_bounds__(512) void rms_k(
    float* __restrict__ X, const float* __restrict__ scale,
    const float* __restrict__ P, float* __restrict__ MWS, float* __restrict__ LPWS,
    float* __restrict__ FPWS, float* __restrict__ OUTFP, int t0, int t1)
{
  if ((int)blockIdx.x < 2) {
    fps_slice(P, MWS, LPWS, FPWS, OUTFP, (int)blockIdx.x, t0, t1);
    return;
  }
  const int tid = threadIdx.x;
  const int w = tid >> 6, lane = tid & 63;
  const long row = (long)((int)blockIdx.x - 2) * 8 + w;
  float2 xv = *(float2*)(X + row * 128 + lane * 2);
  float ss = xv.x * xv.x + xv.y * xv.y;
#pragma unroll
  for (int off = 32; off >= 1; off >>= 1) ss += __shfl_xor(ss, off);
  const float rms = sqrtf(ss) / 11.313708498984761f;
  const float den = rms + 1e-8f;
  const float2 sc = *(const float2*)(scale + lane * 2);
  float2 o;
  o.x = sc.x * (xv.x / den);
  o.y = sc.y * (xv.y / den);
  *(float2*)(X + row * 128 + lane * 2) = o;
}

// ---------------------------------------------------------------------------
// PointPool: h = concat(fp_pos, knn_x) @ Wpool (259x256), LeakyReLU, max over K.
// ---------------------------------------------------------------------------
__global__ __launch_bounds__(256) void pool_k(
    const float* __restrict__ X3, const float* __restrict__ FPWS,
    const int* __restrict__ KIDX, const float* __restrict__ Wp,
    float* __restrict__ OUT)
{
  __shared__ float sh[8][256];
  __shared__ float fp3[3];
  const int bm = blockIdx.x;           // b*2048 + m
  const int b = bm >> 11;
  const int m = bm & 2047;
  const int tid = threadIdx.x;
#pragma unroll
  for (int kk = 0; kk < 8; ++kk) {
    int nbk = KIDX[bm * 8 + kk];
    sh[kk][tid] = X3[(long)(b * N_PTS + nbk) * 256 + tid];
  }
  if (tid < 3) fp3[tid] = FPWS[bm * 3 + tid];
  __syncthreads();
  float base = fp3[0] * Wp[tid] + fp3[1] * Wp[256 + tid] + fp3[2] * Wp[512 + tid];
  float acc[8];
#pragma unroll
  for (int kk = 0; kk < 8; ++kk) acc[kk] = base;
  for (int i = 0; i < 256; i += 2) {
    float w0 = Wp[(3 + i) * 256 + tid];
    float w1 = Wp[(4 + i) * 256 + tid];
#pragma unroll
    for (int kk = 0; kk < 8; ++kk) {
      float2 hh = *(const float2*)&sh[kk][i];
      acc[kk] += hh.x * w0 + hh.y * w1;
    }
  }
  float mx = -INFINITY;
#pragma unroll
  for (int kk = 0; kk < 8; ++kk) {
    float a = acc[kk];
    a = (a >= 0.f) ? a : 0.01f * a;      // LeakyReLU(0.01)
    mx = fmaxf(mx, a);
  }
  OUT[(long)(m * 2 + b) * 256 + tid] = mx;   // (n_out, B, 2D)
}

// ---------------------------------------------------------------------------
extern "C" void kernel_launch(void* const* d_in, const int* in_sizes, int n_in,
                              void* d_out, int out_size, void* d_ws, size_t ws_size,
                              hipStream_t stream)
{
  (void)in_sizes; (void)n_in; (void)out_size; (void)ws_size;
  const float* x    = (const float*)d_in[0];
  const float* ppos = (const float*)d_in[1];
  const float* Wq = (const float*)d_in[2];   const float* bq = (const float*)d_in[3];
  const float* Wk = (const float*)d_in[4];   const float* bk = (const float*)d_in[5];
  const float* Wv = (const float*)d_in[6];   const float* bv = (const float*)d_in[7];
  const float* Wpe1 = (const float*)d_in[8]; const float* bpe1 = (const float*)d_in[9];
  const float* Wpe2 = (const float*)d_in[10];const float* bpe2 = (const float*)d_in[11];
  const float* Wg = (const float*)d_in[12];  const float* bg = (const float*)d_in[13];
  const float* Wo = (const float*)d_in[14];  const float* bo = (const float*)d_in[15];
  const float* scale = (const float*)d_in[16];
  const float* Wf1 = (const float*)d_in[17]; const float* bf1 = (const float*)d_in[18];
  const float* Wf2 = (const float*)d_in[19]; const float* bf2 = (const float*)d_in[20];
  const float* Wpool = (const float*)d_in[21];
  float* out = (float*)d_out;
  char* ws = (char*)d_ws;

  // workspace layout (peak ~49 MB, aliased):
  float* qb   = (float*)(ws);                                   // 8 MB (B,N,128)
  float* kb   = (float*)(ws + (size_t)8 * 1024 * 1024);         // 8 MB
  float* vb   = (float*)(ws + (size_t)16 * 1024 * 1024);        // 8 MB
  float* res  = (float*)(ws + (size_t)24 * 1024 * 1024);        // 8 MB
  float* x2   = (float*)(ws + (size_t)32 * 1024 * 1024);        // 8 MB (N,B,128)
  float* hbuf = (float*)(ws);                                   // 32 MB, aliases qb..res
  float* x3   = (float*)(ws + (size_t)32 * 1024 * 1024);        // 16 MB (B,N,256), aliases x2
  char*  tail = ws + (size_t)48 * 1024 * 1024;
  int*   idx1 = (int*)  (tail);                       // 512 KB
  int*   kidx2= (int*)  (tail + 524288);              // 128 KB
  float* fpws = (float*)(tail + 655360);              // 64 KB slot (48 used)
  float* MWS  = (float*)(tail + 720896);              // 64 KB fps mind state
  float* LPWS = (float*)(tail + 786432);              // 4 KB fps lp state

  // knn1 standalone, full width (256 one-wave blocks)
  knn1_k<<<dim3(128, 2), dim3(64), 0, stream>>>(ppos, ppos, idx1);
  // fps spans (sum = 2048): qkv 3x160, attn 420, Wo 160, rms 80, ffn1 230,
  // ffn2 230, fin 448. fps blocks are blockIdx 0,1 in every 512-thr host.
  gemm2_k<<<dim3(66), dim3(512), 0, stream>>>(x, Wq, bq, qb, nullptr, 1, 128, 128, 1, 0, 0,
                                              ppos, MWS, LPWS, fpws, out, 0, 160);
  gemm2_k<<<dim3(66), dim3(512), 0, stream>>>(x, Wk, bk, kb, nullptr, 1, 128, 128, 1, 0, 0,
                                              ppos, MWS, LPWS, fpws, out, 160, 320);
  gemm2_k<<<dim3(66), dim3(512), 0, stream>>>(x, Wv, bv, vb, nullptr, 1, 128, 128, 1, 0, 0,
                                              ppos, MWS, LPWS, fpws, out, 320, 480);
  attn_k<<<dim3(2050), dim3(512), 0, stream>>>(qb, kb, vb, ppos, idx1,
                                               Wpe1, bpe1, Wpe2, bpe2, Wg, bg, res,
                                               ppos, MWS, LPWS, fpws, out, 480, 900);
  gemm2_k<<<dim3(66), dim3(512), 0, stream>>>(res, Wo, bo, x2, x, 1, 128, 128, 0, 1, 0,
                                              ppos, MWS, LPWS, fpws, out, 900, 1060);
  rms_k<<<dim3(2050), dim3(512), 0, stream>>>(x2, scale,
                                              ppos, MWS, LPWS, fpws, out, 1060, 1140);
  gemm2_k<<<dim3(258), dim3(512), 0, stream>>>(x2, Wf1, bf1, hbuf, nullptr, 4, 512, 128, 0, 0, 1,
                                               ppos, MWS, LPWS, fpws, out, 1140, 1370);
  gemm2_k<<<dim3(130), dim3(512), 0, stream>>>(hbuf, Wf2, bf2, x3, nullptr, 2, 256, 512, 0, 2, 0,
                                               ppos, MWS, LPWS, fpws, out, 1370, 1600);
  fps_fin<<<dim3(2), dim3(512), 0, stream>>>(ppos, MWS, LPWS, fpws, out, 1600, 2048);
  // KNN of fp_pos against all points
  knn2_k<<<dim3(32, 2), dim3(64), 0, stream>>>(fpws, ppos, kidx2);
  // pooling -> output 0
  pool_k<<<dim3(4096), dim3(256), 0, stream>>>(x3, fpws, kidx2, Wpool, out);
}

// Round 10
// 3029.081 us; speedup vs baseline: 1.2370x; 1.2370x over previous
//
#include <hip/hip_runtime.h>
#include <math.h>

// Sizes fixed by the problem
#define N_PTS   8192
#define BATCH   2
#define DIM     128
#define NOUT    2048
#define FPOFF   1048576   // 2048*2*256 floats of output 0
#define SLICE_MAX 512

__device__ __forceinline__ float gelu_f(float v) {
  return 0.5f * v * (1.0f + erff(v * 0.70710678118654752440f));
}

// ---------------------------------------------------------------------------
// stable sorted top-8 insert, reference tie semantics (earlier insert wins)
// ---------------------------------------------------------------------------
__device__ __forceinline__ void knn_insert(float (&dist)[8], int (&idq)[8],
                                           float d2, int ci) {
  if (d2 < dist[7]) {
    float dd = d2;
#pragma unroll
    for (int j = 0; j < 8; ++j) {
      bool cc = dd < dist[j];
      float td = dist[j]; int ti = idq[j];
      dist[j] = cc ? dd : td; idq[j] = cc ? ci : ti;
      dd = cc ? td : dd; ci = cc ? ti : ci;
    }
  }
}

// ---------------------------------------------------------------------------
// FPS slice, 512 threads, 16 slots/thread (R4/R9-proven; ~1.09 us/iter).
// Hosts run this for blockIdx.x < 2 so fps waves start at t=0 of each launch.
// u64 key (d_bits<<32)|~gidx; 6-stage wave butterfly; 8-key block scan via
// parity LDS + ONE barrier; winner coords fetched from global P (input-only,
// L2-hot broadcast). State (mind, lp) persists in ws. Reference-exact math.
// ---------------------------------------------------------------------------
__device__ __forceinline__ void fps_slice(
    const float* __restrict__ P, float* __restrict__ MWS, float* __restrict__ LPWS,
    float* __restrict__ FPWS, float* __restrict__ OUTFP,
    int b, int t0, int t1)
{
  __builtin_amdgcn_s_setprio(3);
  __shared__ unsigned long long wkeys[2][8];
  __shared__ float hist[SLICE_MAX * 3];
  const int tid = threadIdx.x;          // 0..511
  const int wv = tid >> 6;              // 0..7
  const float* __restrict__ Pb = P + (long)b * N_PTS * 3;
  float px[16], py[16], pz[16], mind[16];
#pragma unroll
  for (int s = 0; s < 16; ++s) {
    int i = s * 512 + tid;
    px[s] = Pb[i * 3 + 0];
    py[s] = Pb[i * 3 + 1];
    pz[s] = Pb[i * 3 + 2];
  }
  float lx, ly, lz;
  if (t0 == 0) {
#pragma unroll
    for (int s = 0; s < 16; ++s) mind[s] = INFINITY;
    lx = Pb[0]; ly = Pb[1]; lz = Pb[2];
    if (tid == 0) { hist[0] = lx; hist[1] = ly; hist[2] = lz; }
  } else {
#pragma unroll
    for (int s = 0; s < 16; ++s) mind[s] = MWS[b * N_PTS + s * 512 + tid];
    lx = LPWS[b * 4 + 0]; ly = LPWS[b * 4 + 1]; lz = LPWS[b * 4 + 2];
  }
  const int tstart = (t0 == 0) ? 1 : t0;
  for (int t = tstart; t < t1; ++t) {
    const int par = t & 1;
    float bv = -INFINITY; int bs = 0;
#pragma unroll
    for (int s = 0; s < 16; ++s) {
      float dx = __fsub_rn(px[s], lx);
      float dy = __fsub_rn(py[s], ly);
      float dz = __fsub_rn(pz[s], lz);
      float d = __fadd_rn(__fadd_rn(__fmul_rn(dx, dx), __fmul_rn(dy, dy)), __fmul_rn(dz, dz));
      float mm = fminf(mind[s], d);
      mind[s] = mm;
      bool c = mm > bv;                 // strict > : earliest slot (smallest gidx) wins
      bv = c ? mm : bv; bs = c ? s : bs;
    }
    unsigned long long key =
        ((unsigned long long)__float_as_uint(bv) << 32) |
        (unsigned int)~(unsigned int)(bs * 512 + tid);
#pragma unroll
    for (int off = 1; off <= 32; off <<= 1) {
      unsigned long long o = __shfl_xor(key, off);
      key = (o > key) ? o : key;
    }
    if ((tid & 63) == 0) wkeys[par][wv] = key;   // all lanes converged; lane0 writes
    __syncthreads();
    unsigned long long wk = wkeys[par][0];
#pragma unroll
    for (int u = 1; u < 8; ++u) {
      unsigned long long o = wkeys[par][u];
      wk = (o > wk) ? o : wk;
    }
    const int idx = (int)(~(unsigned int)wk);    // lo32 = ~gidx
    lx = Pb[idx * 3 + 0];
    ly = Pb[idx * 3 + 1];
    lz = Pb[idx * 3 + 2];
    if (tid == 0) {
      int h = (t - t0) * 3;
      hist[h + 0] = lx; hist[h + 1] = ly; hist[h + 2] = lz;
    }
    // next iteration writes the other parity buffer -> one barrier suffices
  }
  // persist state
#pragma unroll
  for (int s = 0; s < 16; ++s) MWS[b * N_PTS + s * 512 + tid] = mind[s];
  if (tid == 0) { LPWS[b * 4 + 0] = lx; LPWS[b * 4 + 1] = ly; LPWS[b * 4 + 2] = lz; }
  __syncthreads();
  const int cnt = (t1 - t0) * 3;
  const long base = ((long)b * NOUT + t0) * 3;
  for (int i = tid; i < cnt; i += 512) {
    float v2 = hist[i];
    FPWS[base + i] = v2;
    OUTFP[FPOFF + base + i] = v2;
  }
  __builtin_amdgcn_s_setprio(0);
}

// standalone finisher
__global__ __launch_bounds__(512) void fps_fin(
    const float* __restrict__ P, float* __restrict__ MWS, float* __restrict__ LPWS,
    float* __restrict__ FPWS, float* __restrict__ OUTFP, int t0, int t1)
{
  fps_slice(P, MWS, LPWS, FPWS, OUTFP, blockIdx.x, t0, t1);
}

// ---------------------------------------------------------------------------
// Fused-pair fp32 GEMM host (512 threads = 2 teams x 256); blocks 0,1 = fps.
// Per team: 128x128 tile, BK=16, 8x(4+4) micro-tile (R4/R9-proven).
// a_mode: 0 direct; 1 arow=(r&8191)*2+(r>>13)
// o_mode: 0 direct; 1 orow=(r&8191)*2+(r>>13); 2 orow=(r&1)*8192+(r>>1)
// ---------------------------------------------------------------------------
__global__ __launch_bounds__(512) void gemm2_k(
    const float* __restrict__ A, const float* __restrict__ W,
    const float* __restrict__ bias, float* __restrict__ OUT,
    const float* __restrict__ resid,
    int nbx, int N, int K, int a_mode, int o_mode, int act,
    const float* __restrict__ P, float* __restrict__ MWS, float* __restrict__ LPWS,
    float* __restrict__ FPWS, float* __restrict__ OUTFP, int t0, int t1)
{
  if ((int)blockIdx.x < 2) {
    fps_slice(P, MWS, LPWS, FPWS, OUTFP, (int)blockIdx.x, t0, t1);
    return;
  }
  const int wid = (int)blockIdx.x - 2;
  __shared__ float As[2][16][132];
  __shared__ float Ws2[2][16][132];
  const int team = threadIdx.x >> 8;
  const int tid = threadIdx.x & 255;
  const int tx = tid & 15, ty = tid >> 4;
  const int bx = wid % nbx;
  const int byy = (wid / nbx) * 2 + team;
  float acc[8][8];
#pragma unroll
  for (int i = 0; i < 8; ++i)
#pragma unroll
    for (int j = 0; j < 8; ++j) acc[i][j] = 0.f;

  for (int k0 = 0; k0 < K; k0 += 16) {
#pragma unroll
    for (int rep = 0; rep < 2; ++rep) {
      int qq = tid + rep * 256;          // 0..511
      int m = qq >> 2, kq = qq & 3;      // A: 128 rows x 16k as float4
      int r = byy * 128 + m;
      int arow = (a_mode == 1) ? ((r & 8191) * 2 + (r >> 13)) : r;
      const float4 av = *(const float4*)(A + (long)arow * K + k0 + kq * 4);
      As[team][kq * 4 + 0][m] = av.x; As[team][kq * 4 + 1][m] = av.y;
      As[team][kq * 4 + 2][m] = av.z; As[team][kq * 4 + 3][m] = av.w;
      int kw = qq >> 5, nq = qq & 31;    // W: 16k x 128 cols
      const float4 wv = *(const float4*)(W + (long)(k0 + kw) * N + bx * 128 + nq * 4);
      *(float4*)&Ws2[team][kw][nq * 4] = wv;
    }
    __syncthreads();
#pragma unroll
    for (int kk = 0; kk < 16; ++kk) {
      float4 a0 = *(const float4*)&As[team][kk][ty * 8];
      float4 a1 = *(const float4*)&As[team][kk][ty * 8 + 4];
      float4 w0 = *(const float4*)&Ws2[team][kk][tx * 4];
      float4 w1 = *(const float4*)&Ws2[team][kk][64 + tx * 4];
      float am[8] = {a0.x, a0.y, a0.z, a0.w, a1.x, a1.y, a1.z, a1.w};
      float wn[8] = {w0.x, w0.y, w0.z, w0.w, w1.x, w1.y, w1.z, w1.w};
#pragma unroll
      for (int i = 0; i < 8; ++i)
#pragma unroll
        for (int j = 0; j < 8; ++j) acc[i][j] += am[i] * wn[j];
    }
    __syncthreads();
  }
  const int c0 = bx * 128 + tx * 4;
  const int c1 = c0 + 64;
  float4 ba = *(const float4*)(bias + c0);
  float4 bb = *(const float4*)(bias + c1);
#pragma unroll
  for (int i = 0; i < 8; ++i) {
    int r = byy * 128 + ty * 8 + i;
    int orow = (o_mode == 1) ? ((r & 8191) * 2 + (r >> 13))
             : (o_mode == 2) ? ((r & 1) * 8192 + (r >> 1)) : r;
    float o[8] = {acc[i][0] + ba.x, acc[i][1] + ba.y, acc[i][2] + ba.z, acc[i][3] + ba.w,
                  acc[i][4] + bb.x, acc[i][5] + bb.y, acc[i][6] + bb.z, acc[i][7] + bb.w};
    if (act == 1) {
#pragma unroll
      for (int j = 0; j < 8; ++j) o[j] = gelu_f(o[j]);
    }
    if (resid) {
      float4 r0 = *(const float4*)(resid + (long)orow * N + c0);
      float4 r1 = *(const float4*)(resid + (long)orow * N + c1);
      o[0] += r0.x; o[1] += r0.y; o[2] += r0.z; o[3] += r0.w;
      o[4] += r1.x; o[5] += r1.y; o[6] += r1.z; o[7] += r1.w;
    }
    *(float4*)(OUT + (long)orow * N + c0) = make_float4(o[0], o[1], o[2], o[3]);
    *(float4*)(OUT + (long)orow * N + c1) = make_float4(o[4], o[5], o[6], o[7]);
  }
}

// ---------------------------------------------------------------------------
// Partial KNN1 host (512 thr); blocks 0,1 = fps. 128 work blocks:
// wid = bid-2; qg = wid>>2 (32 groups of 512 queries); r = wid&3 (cand range).
// Each block: 512 queries scan candidates [r*2048,(r+1)*2048) -> partial
// top-8 to PD/PI at [((b*8192+m)*4 + r)*8 + j]. 8 waves/CU = 2/SIMD.
// ---------------------------------------------------------------------------
__global__ __launch_bounds__(512) void knn1p_k(
    const float* __restrict__ Pp, float* __restrict__ PD, int* __restrict__ PI,
    const float* __restrict__ P, float* __restrict__ MWS, float* __restrict__ LPWS,
    float* __restrict__ FPWS, float* __restrict__ OUTFP, int t0, int t1)
{
  if ((int)blockIdx.x < 2) {
    fps_slice(P, MWS, LPWS, FPWS, OUTFP, (int)blockIdx.x, t0, t1);
    return;
  }
  const int wid = (int)blockIdx.x - 2;   // 0..127
  const int qg = wid >> 2;               // 0..31
  const int r = wid & 3;
  const int b = qg >> 4;                 // 16 groups per batch
  const int m = (qg & 15) * 512 + threadIdx.x;
  __shared__ float4 shp[512];
  const float qx = Pp[(b * N_PTS + m) * 3 + 0];
  const float qy = Pp[(b * N_PTS + m) * 3 + 1];
  const float qz = Pp[(b * N_PTS + m) * 3 + 2];
  const float sqq = __fadd_rn(__fadd_rn(__fmul_rn(qx, qx), __fmul_rn(qy, qy)), __fmul_rn(qz, qz));
  float dist[8]; int idq[8];
#pragma unroll
  for (int j = 0; j < 8; ++j) { dist[j] = INFINITY; idq[j] = 0; }
  const int cb = r * 2048;
  for (int tt = 0; tt < 2048; tt += 512) {
    __syncthreads();
    {
      int l = threadIdx.x;
      float x = Pp[(b * N_PTS + cb + tt + l) * 3 + 0];
      float y = Pp[(b * N_PTS + cb + tt + l) * 3 + 1];
      float z = Pp[(b * N_PTS + cb + tt + l) * 3 + 2];
      float s = __fadd_rn(__fadd_rn(__fmul_rn(x, x), __fmul_rn(y, y)), __fmul_rn(z, z));
      shp[l] = make_float4(x, y, z, s);
    }
    __syncthreads();
    for (int c = 0; c < 512; c += 4) {
      float4 p0 = shp[c + 0];
      float4 p1 = shp[c + 1];
      float4 p2 = shp[c + 2];
      float4 p3 = shp[c + 3];
      float d0 = __fsub_rn(__fadd_rn(sqq, p0.w), __fmul_rn(2.0f,
                 __fadd_rn(__fadd_rn(__fmul_rn(qx, p0.x), __fmul_rn(qy, p0.y)), __fmul_rn(qz, p0.z))));
      float d1 = __fsub_rn(__fadd_rn(sqq, p1.w), __fmul_rn(2.0f,
                 __fadd_rn(__fadd_rn(__fmul_rn(qx, p1.x), __fmul_rn(qy, p1.y)), __fmul_rn(qz, p1.z))));
      float d2 = __fsub_rn(__fadd_rn(sqq, p2.w), __fmul_rn(2.0f,
                 __fadd_rn(__fadd_rn(__fmul_rn(qx, p2.x), __fmul_rn(qy, p2.y)), __fmul_rn(qz, p2.z))));
      float d3 = __fsub_rn(__fadd_rn(sqq, p3.w), __fmul_rn(2.0f,
                 __fadd_rn(__fadd_rn(__fmul_rn(qx, p3.x), __fmul_rn(qy, p3.y)), __fmul_rn(qz, p3.z))));
      float mn = fminf(fminf(d0, d1), fminf(d2, d3));
      if (mn < dist[7]) {
        knn_insert(dist, idq, d0, cb + tt + c + 0);
        knn_insert(dist, idq, d1, cb + tt + c + 1);
        knn_insert(dist, idq, d2, cb + tt + c + 2);
        knn_insert(dist, idq, d3, cb + tt + c + 3);
      }
    }
  }
  const long ob = ((long)(b * N_PTS + m) * 4 + r) * 8;
#pragma unroll
  for (int j = 0; j < 8; ++j) { PD[ob + j] = dist[j]; PI[ob + j] = idq[j]; }
}

// merge 4 partial lists per query -> idx1 (stable: ranges in index order)
__global__ __launch_bounds__(256) void merge1_k(
    const float* __restrict__ PD, const int* __restrict__ PI,
    int* __restrict__ OUTI)
{
  const long g = (long)blockIdx.x * 256 + threadIdx.x;   // 0..16383
  float dist[8]; int idq[8];
#pragma unroll
  for (int j = 0; j < 8; ++j) { dist[j] = INFINITY; idq[j] = 0; }
#pragma unroll
  for (int r = 0; r < 4; ++r) {
    const long ob = (g * 4 + r) * 8;
#pragma unroll
    for (int j = 0; j < 8; ++j) knn_insert(dist, idq, PD[ob + j], PI[ob + j]);
  }
#pragma unroll
  for (int j = 0; j < 8; ++j) OUTI[g * 8 + j] = idq[j];
}

// ---------------------------------------------------------------------------
// Partial KNN2 (standalone, 512 thr, 64 blocks): qg = bid>>3 (8 groups of 512
// of the 4096 fp queries); r = bid&7 -> candidates [r*1024,(r+1)*1024).
// ---------------------------------------------------------------------------
__global__ __launch_bounds__(512) void knn2p_k(
    const float* __restrict__ Q, const float* __restrict__ Pp,
    float* __restrict__ PD, int* __restrict__ PI)
{
  const int qg = (int)blockIdx.x >> 3;   // 0..7
  const int r = (int)blockIdx.x & 7;
  const int b = qg >> 2;                 // 4 groups per batch
  const int m = (qg & 3) * 512 + threadIdx.x;
  __shared__ float4 shp[512];
  const float qx = Q[(b * NOUT + m) * 3 + 0];
  const float qy = Q[(b * NOUT + m) * 3 + 1];
  const float qz = Q[(b * NOUT + m) * 3 + 2];
  const float sqq = __fadd_rn(__fadd_rn(__fmul_rn(qx, qx), __fmul_rn(qy, qy)), __fmul_rn(qz, qz));
  float dist[8]; int idq[8];
#pragma unroll
  for (int j = 0; j < 8; ++j) { dist[j] = INFINITY; idq[j] = 0; }
  const int cb = r * 1024;
  for (int tt = 0; tt < 1024; tt += 512) {
    __syncthreads();
    {
      int l = threadIdx.x;
      float x = Pp[(b * N_PTS + cb + tt + l) * 3 + 0];
      float y = Pp[(b * N_PTS + cb + tt + l) * 3 + 1];
      float z = Pp[(b * N_PTS + cb + tt + l) * 3 + 2];
      float s = __fadd_rn(__fadd_rn(__fmul_rn(x, x), __fmul_rn(y, y)), __fmul_rn(z, z));
      shp[l] = make_float4(x, y, z, s);
    }
    __syncthreads();
    for (int c = 0; c < 512; c += 4) {
      float4 p0 = shp[c + 0];
      float4 p1 = shp[c + 1];
      float4 p2 = shp[c + 2];
      float4 p3 = shp[c + 3];
      float d0 = __fsub_rn(__fadd_rn(sqq, p0.w), __fmul_rn(2.0f,
                 __fadd_rn(__fadd_rn(__fmul_rn(qx, p0.x), __fmul_rn(qy, p0.y)), __fmul_rn(qz, p0.z))));
      float d1 = __fsub_rn(__fadd_rn(sqq, p1.w), __fmul_rn(2.0f,
                 __fadd_rn(__fadd_rn(__fmul_rn(qx, p1.x), __fmul_rn(qy, p1.y)), __fmul_rn(qz, p1.z))));
      float d2 = __fsub_rn(__fadd_rn(sqq, p2.w), __fmul_rn(2.0f,
                 __fadd_rn(__fadd_rn(__fmul_rn(qx, p2.x), __fmul_rn(qy, p2.y)), __fmul_rn(qz, p2.z))));
      float d3 = __fsub_rn(__fadd_rn(sqq, p3.w), __fmul_rn(2.0f,
                 __fadd_rn(__fadd_rn(__fmul_rn(qx, p3.x), __fmul_rn(qy, p3.y)), __fmul_rn(qz, p3.z))));
      float mn = fminf(fminf(d0, d1), fminf(d2, d3));
      if (mn < dist[7]) {
        knn_insert(dist, idq, d0, cb + tt + c + 0);
        knn_insert(dist, idq, d1, cb + tt + c + 1);
        knn_insert(dist, idq, d2, cb + tt + c + 2);
        knn_insert(dist, idq, d3, cb + tt + c + 3);
      }
    }
  }
  const long ob = ((long)(b * NOUT + m) * 8 + r) * 8;
#pragma unroll
  for (int j = 0; j < 8; ++j) { PD[ob + j] = dist[j]; PI[ob + j] = idq[j]; }
}

// merge 8 partial lists per fp query -> kidx2
__global__ __launch_bounds__(256) void merge2_k(
    const float* __restrict__ PD, const int* __restrict__ PI,
    int* __restrict__ OUTI)
{
  const long g = (long)blockIdx.x * 256 + threadIdx.x;   // 0..4095
  float dist[8]; int idq[8];
#pragma unroll
  for (int j = 0; j < 8; ++j) { dist[j] = INFINITY; idq[j] = 0; }
#pragma unroll
  for (int r = 0; r < 8; ++r) {
    const long ob = (g * 8 + r) * 8;
#pragma unroll
    for (int j = 0; j < 8; ++j) knn_insert(dist, idq, PD[ob + j], PI[ob + j]);
  }
#pragma unroll
  for (int j = 0; j < 8; ++j) OUTI[g * 8 + j] = idq[j];
}

// ---------------------------------------------------------------------------
// Fused neighbor attention, 512-thr host (8 waves = 8 points); blocks 0,1=fps.
// ---------------------------------------------------------------------------
__global__ __launch_bounds__(512) void attn_k(
    const float* __restrict__ Qb, const float* __restrict__ Kb, const float* __restrict__ Vb,
    const float* __restrict__ Pp, const int* __restrict__ IDX,
    const float* __restrict__ Wpe1, const float* __restrict__ bpe1,
    const float* __restrict__ Wpe2, const float* __restrict__ bpe2,
    const float* __restrict__ Wg, const float* __restrict__ bg,
    float* __restrict__ RES,
    const float* __restrict__ P, float* __restrict__ MWS, float* __restrict__ LPWS,
    float* __restrict__ FPWS, float* __restrict__ OUTFP, int t0, int t1)
{
  if ((int)blockIdx.x < 2) {
    fps_slice(P, MWS, LPWS, FPWS, OUTFP, (int)blockIdx.x, t0, t1);
    return;
  }
  __shared__ float sbuf[8][1024];
  const int tid = threadIdx.x;
  const int w = tid >> 6, lane = tid & 63;
  const int g = ((int)blockIdx.x - 2) * 8 + w;   // 0..16383 : b*8192+n
  const int b = g >> 13, n = g & 8191;
  const int j0 = lane * 2;
  float* sb = sbuf[w];
  const float2 qv = *(const float2*)(Qb + (long)g * 128 + j0);
  int nb[8];
#pragma unroll
  for (int kk = 0; kk < 8; ++kk) nb[kk] = IDX[g * 8 + kk];
  const float p0 = Pp[(b * N_PTS + n) * 3 + 0];
  const float p1 = Pp[(b * N_PTS + n) * 3 + 1];
  const float p2 = Pp[(b * N_PTS + n) * 3 + 2];
  // phase A: h1 = gelu(rel @ Wpe1 + bpe1) -> LDS
  const float2 w1a = *(const float2*)(Wpe1 + j0);
  const float2 w1b = *(const float2*)(Wpe1 + 128 + j0);
  const float2 w1c = *(const float2*)(Wpe1 + 256 + j0);
  const float2 b1 = *(const float2*)(bpe1 + j0);
#pragma unroll
  for (int kk = 0; kk < 8; ++kk) {
    const float* pn = Pp + (long)(b * N_PTS + nb[kk]) * 3;
    float r0 = p0 - pn[0], r1 = p1 - pn[1], r2 = p2 - pn[2];
    float h0 = r0 * w1a.x + r1 * w1b.x + r2 * w1c.x + b1.x;
    float h1 = r0 * w1a.y + r1 * w1b.y + r2 * w1c.y + b1.y;
    sb[kk * 128 + j0]     = gelu_f(h0);
    sb[kk * 128 + j0 + 1] = gelu_f(h1);
  }
  __syncthreads();
  // phase B: pe = h1 @ Wpe2
  float2 pe[8];
#pragma unroll
  for (int kk = 0; kk < 8; ++kk) pe[kk] = make_float2(0.f, 0.f);
  for (int i = 0; i < 128; i += 2) {
    float2 wa = *(const float2*)(Wpe2 + (long)i * 128 + j0);
    float2 wb = *(const float2*)(Wpe2 + (long)(i + 1) * 128 + j0);
#pragma unroll
    for (int kk = 0; kk < 8; ++kk) {
      float2 hh = *(const float2*)&sb[kk * 128 + i];
      pe[kk].x += hh.x * wa.x + hh.y * wb.x;
      pe[kk].y += hh.x * wa.y + hh.y * wb.y;
    }
  }
  const float2 b2v = *(const float2*)(bpe2 + j0);
  __syncthreads();
  // t = q - k_nb + pe  -> LDS (reuse buffer)
#pragma unroll
  for (int kk = 0; kk < 8; ++kk) {
    pe[kk].x += b2v.x; pe[kk].y += b2v.y;
    const float2 kv = *(const float2*)(Kb + (long)(b * N_PTS + nb[kk]) * 128 + j0);
    sb[kk * 128 + j0]     = qv.x - kv.x + pe[kk].x;
    sb[kk * 128 + j0 + 1] = qv.y - kv.y + pe[kk].y;
  }
  __syncthreads();
  // phase C: a = t @ Wg
  float2 av[8];
#pragma unroll
  for (int kk = 0; kk < 8; ++kk) av[kk] = make_float2(0.f, 0.f);
  for (int i = 0; i < 128; i += 2) {
    float2 wa = *(const float2*)(Wg + (long)i * 128 + j0);
    float2 wb = *(const float2*)(Wg + (long)(i + 1) * 128 + j0);
#pragma unroll
    for (int kk = 0; kk < 8; ++kk) {
      float2 tt = *(const float2*)&sb[kk * 128 + i];
      av[kk].x += tt.x * wa.x + tt.y * wb.x;
      av[kk].y += tt.x * wa.y + tt.y * wb.y;
    }
  }
  const float2 bgv = *(const float2*)(bg + j0);
  float2 resv = make_float2(0.f, 0.f);
  const float sd = 11.313708498984761f;   // sqrt(128)
#pragma unroll
  for (int kk = 0; kk < 8; ++kk) {
    float l0 = (av[kk].x + bgv.x) / sd;
    float l1 = (av[kk].y + bgv.y) / sd;
    float mx = fmaxf(l0, l1);
#pragma unroll
    for (int off = 32; off >= 1; off >>= 1) mx = fmaxf(mx, __shfl_xor(mx, off));
    float e0 = expf(l0 - mx), e1 = expf(l1 - mx);
    float sm = e0 + e1;
#pragma unroll
    for (int off = 32; off >= 1; off >>= 1) sm += __shfl_xor(sm, off);
    const float2 vv = *(const float2*)(Vb + (long)(b * N_PTS + nb[kk]) * 128 + j0);
    resv.x += (e0 / sm) * (vv.x + pe[kk].x);
    resv.y += (e1 / sm) * (vv.y + pe[kk].y);
  }
  *(float2*)(RES + (long)g * 128 + j0) = resv;
}

// ---------------------------------------------------------------------------
// RMSNorm in-place, 512-thr host (8 rows/block); blocks 0,1 = fps.
// ---------------------------------------------------------------------------
__global__ __launch_bounds__(512) void rms_k(
    float* __restrict__ X, const float* __restrict__ scale,
    const float* __restrict__ P, float* __restrict__ MWS, float* __restrict__ LPWS,
    float* __restrict__ FPWS, float* __restrict__ OUTFP, int t0, int t1)
{
  if ((int)blockIdx.x < 2) {
    fps_slice(P, MWS, LPWS, FPWS, OUTFP, (int)blockIdx.x, t0, t1);
    return;
  }
  const int tid = threadIdx.x;
  const int w = tid >> 6, lane = tid & 63;
  const long row = (long)((int)blockIdx.x - 2) * 8 + w;
  float2 xv = *(float2*)(X + row * 128 + lane * 2);
  float ss = xv.x * xv.x + xv.y * xv.y;
#pragma unroll
  for (int off = 32; off >= 1; off >>= 1) ss += __shfl_xor(ss, off);
  const float rms = sqrtf(ss) / 11.313708498984761f;
  const float den = rms + 1e-8f;
  const float2 sc = *(const float2*)(scale + lane * 2);
  float2 o;
  o.x = sc.x * (xv.x / den);
  o.y = sc.y * (xv.y / den);
  *(float2*)(X + row * 128 + lane * 2) = o;
}

// ---------------------------------------------------------------------------
// PointPool: h = concat(fp_pos, knn_x) @ Wpool (259x256), LeakyReLU, max over K.
// ---------------------------------------------------------------------------
__global__ __launch_bounds__(256) void pool_k(
    const float* __restrict__ X3, const float* __restrict__ FPWS,
    const int* __restrict__ KIDX, const float* __restrict__ Wp,
    float* __restrict__ OUT)
{
  __shared__ float sh[8][256];
  __shared__ float fp3[3];
  const int bm = blockIdx.x;           // b*2048 + m
  const int b = bm >> 11;
  const int m = bm & 2047;
  const int tid = threadIdx.x;
#pragma unroll
  for (int kk = 0; kk < 8; ++kk) {
    int nbk = KIDX[bm * 8 + kk];
    sh[kk][tid] = X3[(long)(b * N_PTS + nbk) * 256 + tid];
  }
  if (tid < 3) fp3[tid] = FPWS[bm * 3 + tid];
  __syncthreads();
  float base = fp3[0] * Wp[tid] + fp3[1] * Wp[256 + tid] + fp3[2] * Wp[512 + tid];
  float acc[8];
#pragma unroll
  for (int kk = 0; kk < 8; ++kk) acc[kk] = base;
  for (int i = 0; i < 256; i += 2) {
    float w0 = Wp[(3 + i) * 256 + tid];
    float w1 = Wp[(4 + i) * 256 + tid];
#pragma unroll
    for (int kk = 0; kk < 8; ++kk) {
      float2 hh = *(const float2*)&sh[kk][i];
      acc[kk] += hh.x * w0 + hh.y * w1;
    }
  }
  float mx = -INFINITY;
#pragma unroll
  for (int kk = 0; kk < 8; ++kk) {
    float a = acc[kk];
    a = (a >= 0.f) ? a : 0.01f * a;      // LeakyReLU(0.01)
    mx = fmaxf(mx, a);
  }
  OUT[(long)(m * 2 + b) * 256 + tid] = mx;   // (n_out, B, 2D)
}

// ---------------------------------------------------------------------------
extern "C" void kernel_launch(void* const* d_in, const int* in_sizes, int n_in,
                              void* d_out, int out_size, void* d_ws, size_t ws_size,
                              hipStream_t stream)
{
  (void)in_sizes; (void)n_in; (void)out_size; (void)ws_size;
  const float* x    = (const float*)d_in[0];
  const float* ppos = (const float*)d_in[1];
  const float* Wq = (const float*)d_in[2];   const float* bq = (const float*)d_in[3];
  const float* Wk = (const float*)d_in[4];   const float* bk = (const float*)d_in[5];
  const float* Wv = (const float*)d_in[6];   const float* bv = (const float*)d_in[7];
  const float* Wpe1 = (const float*)d_in[8]; const float* bpe1 = (const float*)d_in[9];
  const float* Wpe2 = (const float*)d_in[10];const float* bpe2 = (const float*)d_in[11];
  const float* Wg = (const float*)d_in[12];  const float* bg = (const float*)d_in[13];
  const float* Wo = (const float*)d_in[14];  const float* bo = (const float*)d_in[15];
  const float* scale = (const float*)d_in[16];
  const float* Wf1 = (const float*)d_in[17]; const float* bf1 = (const float*)d_in[18];
  const float* Wf2 = (const float*)d_in[19]; const float* bf2 = (const float*)d_in[20];
  const float* Wpool = (const float*)d_in[21];
  float* out = (float*)d_out;
  char* ws = (char*)d_ws;

  // workspace layout (peak ~49 MB, aliased):
  float* qb   = (float*)(ws);                                   // 8 MB (B,N,128)
  float* kb   = (float*)(ws + (size_t)8 * 1024 * 1024);         // 8 MB
  float* vb   = (float*)(ws + (size_t)16 * 1024 * 1024);        // 8 MB
  float* res  = (float*)(ws + (size_t)24 * 1024 * 1024);        // 8 MB
  float* x2   = (float*)(ws + (size_t)32 * 1024 * 1024);        // 8 MB (N,B,128)
  float* hbuf = (float*)(ws);                                   // 32 MB, aliases qb..res
  float* x3   = (float*)(ws + (size_t)32 * 1024 * 1024);        // 16 MB (B,N,256), aliases x2
  // KNN partials live in dead aliased regions:
  float* PD1  = (float*)(ws + (size_t)24 * 1024 * 1024);        // 2 MB, in res slot (dead before attn writes res)
  int*   PI1  = (int*)  (ws + (size_t)26 * 1024 * 1024);        // 2 MB
  float* PD2  = (float*)(ws);                                   // 1 MB, hbuf dead after ffn2
  int*   PI2  = (int*)  (ws + (size_t)1 * 1024 * 1024);         // 1 MB
  char*  tail = ws + (size_t)48 * 1024 * 1024;
  int*   idx1 = (int*)  (tail);                       // 512 KB
  int*   kidx2= (int*)  (tail + 524288);              // 128 KB
  float* fpws = (float*)(tail + 655360);              // 64 KB slot (48 used)
  float* MWS  = (float*)(tail + 720896);              // 64 KB fps mind state
  float* LPWS = (float*)(tail + 786432);              // 4 KB fps lp state

  // fps spans (sum = 2048): qkv 3x130, knn1p 150, attn 420, Wo 130, rms 60,
  // ffn1 230, ffn2 190, fin 478. fps blocks are blockIdx 0,1 in every host.
  gemm2_k<<<dim3(66), dim3(512), 0, stream>>>(x, Wq, bq, qb, nullptr, 1, 128, 128, 1, 0, 0,
                                              ppos, MWS, LPWS, fpws, out, 0, 130);
  gemm2_k<<<dim3(66), dim3(512), 0, stream>>>(x, Wk, bk, kb, nullptr, 1, 128, 128, 1, 0, 0,
                                              ppos, MWS, LPWS, fpws, out, 130, 260);
  gemm2_k<<<dim3(66), dim3(512), 0, stream>>>(x, Wv, bv, vb, nullptr, 1, 128, 128, 1, 0, 0,
                                              ppos, MWS, LPWS, fpws, out, 260, 390);
  // partial self-KNN (hosted) + merge
  knn1p_k<<<dim3(130), dim3(512), 0, stream>>>(ppos, PD1, PI1,
                                               ppos, MWS, LPWS, fpws, out, 390, 540);
  merge1_k<<<dim3(64), dim3(256), 0, stream>>>(PD1, PI1, idx1);
  attn_k<<<dim3(2050), dim3(512), 0, stream>>>(qb, kb, vb, ppos, idx1,
                                               Wpe1, bpe1, Wpe2, bpe2, Wg, bg, res,
                                               ppos, MWS, LPWS, fpws, out, 540, 960);
  gemm2_k<<<dim3(66), dim3(512), 0, stream>>>(res, Wo, bo, x2, x, 1, 128, 128, 0, 1, 0,
                                              ppos, MWS, LPWS, fpws, out, 960, 1090);
  rms_k<<<dim3(2050), dim3(512), 0, stream>>>(x2, scale,
                                              ppos, MWS, LPWS, fpws, out, 1090, 1150);
  gemm2_k<<<dim3(258), dim3(512), 0, stream>>>(x2, Wf1, bf1, hbuf, nullptr, 4, 512, 128, 0, 0, 1,
                                               ppos, MWS, LPWS, fpws, out, 1150, 1380);
  gemm2_k<<<dim3(130), dim3(512), 0, stream>>>(hbuf, Wf2, bf2, x3, nullptr, 2, 256, 512, 0, 2, 0,
                                               ppos, MWS, LPWS, fpws, out, 1380, 1570);
  fps_fin<<<dim3(2), dim3(512), 0, stream>>>(ppos, MWS, LPWS, fpws, out, 1570, 2048);
  // partial KNN of fp_pos + merge
  knn2p_k<<<dim3(64), dim3(512), 0, stream>>>(fpws, ppos, PD2, PI2);
  merge2_k<<<dim3(16), dim3(256), 0, stream>>>(PD2, PI2, kidx2);
  // pooling -> output 0
  pool_k<<<dim3(4096), dim3(256), 0, stream>>>(x3, fpws, kidx2, Wpool, out);
}